// Round 2
// baseline (180.379 us; speedup 1.0000x reference)
//
#include <hip/hip_runtime.h>

// Problem constants (from reference):
//   confidence_maps: (8, 6, 4, 512, 512) f32
//   warp_masks:      (8, 1, 512, 512)    f32
//   gauss_kernel:    (1, 1, 5, 5)        f32
// Output: mask (48, 1, 512, 512) f32  +  rate scalar f32  => 12,582,913 floats.
//
// Simplifications (validated round 1, absmax 0.0):
//  - rate == 0.5 exactly; ego rows (l==0) are all-ones, no compute.
//  - max_c(sigmoid) == sigmoid(max_c); f64 math matches np reference ordering.
//
// Round-2 changes:
//  - compute_kernel: 512 threads, LDS 39.2 KB -> 4 blocks/CU (100% occ target).
//  - no f64 sm array: store 32-bit quantization keys only (42 MB), all
//    selection passes stream u32; exact f64 values for the few cutoff-cell
//    candidates are recomputed bit-identically in finalize (shared m_val +
//    explicit fma chain, identical op order in both kernels).

#define NROWSEL 40            // rows with l != 0
#define NPIX    262144        // 512*512
#define KSEL    131072u       // int(HW * 0.5)
#define CAND_CAP 8192

// ---- workspace layout (bytes) ----
#define OFF_KEY  0ull                          // 40*262144 u32 = 41,943,040
#define OFF_H1   41943040ull                   // 40*512  u32   =     81,920
#define OFF_H2   42024960ull                   // 40*2048 u32   =    327,680
#define OFF_ST   42352640ull                   // 40*4 int      =        640
#define OFF_CC   42353280ull                   // 40 u32        =        160
#define OFF_CI   42353440ull                   // 40*8192 int   =  1,310,720
#define META_BYTES 410560ull                   // zero H1..CC

__device__ __forceinline__ unsigned qkey(double v) {
  // monotone non-decreasing 32-bit key for v in [0,1)
  double t = v * 4294967296.0;
  t = fmax(t, 0.0);
  t = fmin(t, 4294967295.0);
  return (unsigned)t;
}

// m = sigmoid(max_c conf) * warp, f64, zero outside image. Shared between
// compute_kernel and finalize_kernel so values are BIT-IDENTICAL.
__device__ __forceinline__ double m_val(const float* __restrict__ confr,
                                        const float* __restrict__ warpr,
                                        int gy, int gx) {
  if (gy < 0 || gy >= 512 || gx < 0 || gx >= 512) return 0.0;
  int off = gy * 512 + gx;
  float x0 = confr[off];
  float x1 = confr[NPIX + off];
  float x2 = confr[2 * NPIX + off];
  float x3 = confr[3 * NPIX + off];
  float mx = fmaxf(fmaxf(x0, x1), fmaxf(x2, x3));
  double s = 1.0 / (1.0 + exp(-(double)mx));
  return s * (double)warpr[off];
}

// Fill the 8 ego rows (l==0) with 1.0
__global__ void ego_fill_kernel(float* __restrict__ out) {
  int i = blockIdx.x * 256 + threadIdx.x;       // 0 .. 524287 (float4 units)
  int b = i >> 16;                               // 65536 float4 per row
  int o4 = i & 65535;
  float4* p = (float4*)(out + (size_t)b * 6u * NPIX) + o4;
  *p = make_float4(1.f, 1.f, 1.f, 1.f);
}

// Fused: m (f64) halo tile in LDS, 5x5 gaussian conv (fma chain), write u32
// key, build 512-bin level-1 histogram in LDS.
__global__ __launch_bounds__(512, 8) void compute_kernel(
    const float* __restrict__ conf, const float* __restrict__ warp,
    const float* __restrict__ gk, unsigned* __restrict__ keys,
    unsigned* __restrict__ hist1) {
  const int blk = blockIdx.x;        // NROWSEL * 64
  const int j = blk >> 6;            // selected-row index 0..39
  const int tile = blk & 63;         // 8x8 tiles of 64x64
  const int ty0 = (tile >> 3) << 6;
  const int tx0 = (tile & 7) << 6;
  const int b = j / 5;
  const int l = j % 5 + 1;
  const int rowg = b * 6 + l;
  const float* confr = conf + (size_t)rowg * 4u * NPIX;
  const float* warpr = warp + (size_t)b * NPIX;

  __shared__ double mt[68][68];      // 36992 B
  __shared__ double g[25];           //   200 B
  __shared__ unsigned lh[512];       //  2048 B   => 39240 B total
  const int tid = threadIdx.x;
  if (tid < 25) g[tid] = (double)gk[tid];
  if (tid < 512) lh[tid] = 0u;

  // load 68x68 halo of m
  for (int i = tid; i < 68 * 68; i += 512) {
    int hy = i / 68, hx = i % 68;
    mt[hy][hx] = m_val(confr, warpr, ty0 + hy - 2, tx0 + hx - 2);
  }
  __syncthreads();

  const int txl = tid & 63;
  const int tyl = tid >> 6;           // wave index 0..7
  unsigned* keyrow = keys + (size_t)j * NPIX;
  for (int rr = 0; rr < 8; ++rr) {
    int yy = tyl + (rr << 3);         // 0..63
    double acc = 0.0;
#pragma unroll
    for (int dy = 0; dy < 5; ++dy)
#pragma unroll
      for (int dx = 0; dx < 5; ++dx)
        acc = fma(g[dy * 5 + dx], mt[yy + dy][txl + dx], acc);
    unsigned k = qkey(acc);
    keyrow[(ty0 + yy) * 512 + (tx0 + txl)] = k;
    atomicAdd(&lh[k >> 23], 1u);
  }
  __syncthreads();
  unsigned* h1 = hist1 + j * 512;
  if (tid < 512 && lh[tid]) atomicAdd(&h1[tid], lh[tid]);
}

// Level 1: find bin b1 (descending, 512 bins = key bits [31:23]); A1 above.
__global__ void scan1_kernel(const unsigned* __restrict__ hist1,
                             int* __restrict__ st) {
  int j = blockIdx.x;
  const unsigned* h = hist1 + j * 512;
  __shared__ unsigned cs[256];
  int tid = threadIdx.x;
  cs[tid] = h[tid * 2] + h[tid * 2 + 1];
  __syncthreads();
  if (tid == 0) {
    unsigned cum = 0; int b1 = 0; unsigned A1 = 0;
    for (int c = 255; c >= 0; --c) {
      if (cum + cs[c] >= KSEL) {
        unsigned cc = cum;
        for (int k = 1; k >= 0; --k) {
          unsigned hv = h[c * 2 + k];
          if (cc + hv >= KSEL) { b1 = c * 2 + k; A1 = cc; break; }
          cc += hv;
        }
        break;
      }
      cum += cs[c];
    }
    st[j * 4 + 0] = b1;
    st[j * 4 + 1] = (int)A1;
  }
}

// Level 2: histogram of key bits [22:12] for keys in bin b1 (u32 stream).
__global__ __launch_bounds__(256) void hist2_kernel(
    const unsigned* __restrict__ keys, const int* __restrict__ st,
    unsigned* __restrict__ hist2) {
  int blk = blockIdx.x;
  int j = blk >> 6, seg = blk & 63;
  unsigned b1 = (unsigned)st[j * 4 + 0];
  const uint4* kp = (const uint4*)(keys + (size_t)j * NPIX + seg * 4096);
  __shared__ unsigned lh[2048];
  for (int i = threadIdx.x; i < 2048; i += 256) lh[i] = 0u;
  __syncthreads();
#pragma unroll
  for (int it = 0; it < 4; ++it) {
    uint4 k4 = kp[threadIdx.x + it * 256];
    if ((k4.x >> 23) == b1) atomicAdd(&lh[(k4.x >> 12) & 2047u], 1u);
    if ((k4.y >> 23) == b1) atomicAdd(&lh[(k4.y >> 12) & 2047u], 1u);
    if ((k4.z >> 23) == b1) atomicAdd(&lh[(k4.z >> 12) & 2047u], 1u);
    if ((k4.w >> 23) == b1) atomicAdd(&lh[(k4.w >> 12) & 2047u], 1u);
  }
  __syncthreads();
  unsigned* h2 = hist2 + j * 2048;
  for (int i = threadIdx.x; i < 2048; i += 256)
    if (lh[i]) atomicAdd(&h2[i], lh[i]);
}

// Within bin b1, find sub-bin b2; A2 = count strictly above prefix (b1,b2).
__global__ void scan2_kernel(const unsigned* __restrict__ hist2,
                             int* __restrict__ st) {
  int j = blockIdx.x;
  const unsigned* h = hist2 + j * 2048;
  __shared__ unsigned cs[256];
  int tid = threadIdx.x;
  unsigned s = 0;
  for (int k = 0; k < 8; ++k) s += h[tid * 8 + k];
  cs[tid] = s;
  __syncthreads();
  if (tid == 0) {
    unsigned A1 = (unsigned)st[j * 4 + 1];
    unsigned cum = A1; int b2 = 0; unsigned A2 = A1;
    for (int c = 255; c >= 0; --c) {
      if (cum + cs[c] >= KSEL) {
        unsigned cc = cum;
        for (int k = 7; k >= 0; --k) {
          unsigned hv = h[c * 8 + k];
          if (cc + hv >= KSEL) { b2 = c * 8 + k; A2 = cc; break; }
          cc += hv;
        }
        break;
      }
      cum += cs[c];
    }
    st[j * 4 + 2] = b2;
    st[j * 4 + 3] = (int)A2;
  }
}

// Write decided mask bits from keys (vectorized); gather cutoff candidates.
__global__ __launch_bounds__(256) void mask_gather_kernel(
    const unsigned* __restrict__ keys, const int* __restrict__ st,
    float* __restrict__ out, unsigned* __restrict__ ccount,
    int* __restrict__ cidx) {
  int blk = blockIdx.x;
  int j = blk >> 6, seg = blk & 63;
  int b = j / 5, l = j % 5 + 1;
  int rowg = b * 6 + l;
  unsigned b1 = (unsigned)st[j * 4 + 0];
  unsigned b2 = (unsigned)st[j * 4 + 2];
  unsigned pstar = (b1 << 11) | b2;
  const uint4* kp = (const uint4*)(keys + (size_t)j * NPIX + seg * 4096);
  float4* o4 = (float4*)(out + (size_t)rowg * NPIX + seg * 4096);
#pragma unroll
  for (int it = 0; it < 4; ++it) {
    int i4 = threadIdx.x + it * 256;
    uint4 k4 = kp[i4];
    float4 mv;
    unsigned p;
    p = k4.x >> 12; mv.x = p > pstar ? 1.f : 0.f;
    if (p == pstar) { unsigned s = atomicAdd(&ccount[j], 1u); if (s < CAND_CAP) cidx[j * CAND_CAP + s] = seg * 4096 + i4 * 4 + 0; }
    p = k4.y >> 12; mv.y = p > pstar ? 1.f : 0.f;
    if (p == pstar) { unsigned s = atomicAdd(&ccount[j], 1u); if (s < CAND_CAP) cidx[j * CAND_CAP + s] = seg * 4096 + i4 * 4 + 1; }
    p = k4.z >> 12; mv.z = p > pstar ? 1.f : 0.f;
    if (p == pstar) { unsigned s = atomicAdd(&ccount[j], 1u); if (s < CAND_CAP) cidx[j * CAND_CAP + s] = seg * 4096 + i4 * 4 + 2; }
    p = k4.w >> 12; mv.w = p > pstar ? 1.f : 0.f;
    if (p == pstar) { unsigned s = atomicAdd(&ccount[j], 1u); if (s < CAND_CAP) cidx[j * CAND_CAP + s] = seg * 4096 + i4 * 4 + 3; }
    o4[i4] = mv;
  }
}

// Recompute exact f64 values for candidates (bit-identical to compute_kernel),
// exact rank with (value desc, index asc) tie-break, set top R = K - A2.
__global__ void finalize_kernel(const float* __restrict__ conf,
                                const float* __restrict__ warp,
                                const float* __restrict__ gk,
                                const int* __restrict__ st,
                                const unsigned* __restrict__ ccount,
                                const int* __restrict__ cidx,
                                float* __restrict__ out) {
  int j = blockIdx.x;
  int b = j / 5, l = j % 5 + 1;
  int rowg = b * 6 + l;
  const float* confr = conf + (size_t)rowg * 4u * NPIX;
  const float* warpr = warp + (size_t)b * NPIX;
  __shared__ double vs[CAND_CAP];    // 64 KB
  __shared__ int ids[CAND_CAP];      // 32 KB
  __shared__ double g[25];
  int tid = threadIdx.x;
  if (tid < 25) g[tid] = (double)gk[tid];
  unsigned A2 = (unsigned)st[j * 4 + 3];
  int R = (int)(KSEL - A2);
  int C = (int)min(ccount[j], (unsigned)CAND_CAP);
  __syncthreads();
  for (int i = tid; i < C; i += 256) {
    int idx = cidx[j * CAND_CAP + i];
    int y = idx >> 9, x = idx & 511;
    double acc = 0.0;
    for (int dy = 0; dy < 5; ++dy)
      for (int dx = 0; dx < 5; ++dx)
        acc = fma(g[dy * 5 + dx], m_val(confr, warpr, y + dy - 2, x + dx - 2), acc);
    vs[i] = acc;
    ids[i] = idx;
  }
  __syncthreads();
  for (int i = tid; i < C; i += 256) {
    double vi = vs[i];
    int ii = ids[i];
    int rank = 0;
    for (int q = 0; q < C; ++q) {
      double vq = vs[q];
      rank += (vq > vi) || (vq == vi && ids[q] < ii) ? 1 : 0;
    }
    if (rank < R) out[(size_t)rowg * NPIX + ii] = 1.0f;
  }
  if (j == 0 && tid == 0) out[12582912] = 0.5f;  // rate == 0.5 exactly
}

extern "C" void kernel_launch(void* const* d_in, const int* in_sizes, int n_in,
                              void* d_out, int out_size, void* d_ws, size_t ws_size,
                              hipStream_t stream) {
  const float* conf = (const float*)d_in[0];
  const float* warp = (const float*)d_in[1];
  const float* gk   = (const float*)d_in[2];
  float* out = (float*)d_out;
  char* ws = (char*)d_ws;

  unsigned* keys = (unsigned*)(ws + OFF_KEY);
  unsigned* h1   = (unsigned*)(ws + OFF_H1);
  unsigned* h2   = (unsigned*)(ws + OFF_H2);
  int*      st   = (int*)(ws + OFF_ST);
  unsigned* cc   = (unsigned*)(ws + OFF_CC);
  int*      ci   = (int*)(ws + OFF_CI);

  hipMemsetAsync(ws + OFF_H1, 0, (size_t)META_BYTES, stream);

  ego_fill_kernel<<<2048, 256, 0, stream>>>(out);
  compute_kernel<<<NROWSEL * 64, 512, 0, stream>>>(conf, warp, gk, keys, h1);
  scan1_kernel<<<NROWSEL, 256, 0, stream>>>(h1, st);
  hist2_kernel<<<NROWSEL * 64, 256, 0, stream>>>(keys, st, h2);
  scan2_kernel<<<NROWSEL, 256, 0, stream>>>(h2, st);
  mask_gather_kernel<<<NROWSEL * 64, 256, 0, stream>>>(keys, st, out, cc, ci);
  finalize_kernel<<<NROWSEL, 256, 0, stream>>>(conf, warp, gk, st, cc, ci, out);
}